// Round 10
// baseline (243.853 us; speedup 1.0000x reference)
//
#include <hip/hip_runtime.h>
#include <math.h>

#define EPS 1e-6f
#define NB 4096
#define NN 64

typedef __attribute__((ext_vector_type(8))) short short8_t;
typedef __attribute__((ext_vector_type(4))) float f32x4;
typedef __attribute__((ext_vector_type(4))) unsigned u32x4;
typedef __attribute__((ext_vector_type(2))) unsigned u32x2;

// one instruction: packs {bf16(a), bf16(b)} (RNE) into 32 bits
__device__ __forceinline__ unsigned cvtpk(float a, float b) {
  unsigned r;
  asm("v_cvt_pk_bf16_f32 %0, %1, %2" : "=v"(r) : "v"(a), "v"(b));
  return r;
}
// split two f32 into packed bf16 hi + packed bf16 lo (2-term split)
__device__ __forceinline__ unsigned split2(float a, float b, unsigned& lo) {
  unsigned h = cvtpk(a, b);
  float ra = __uint_as_float(h << 16);
  float rb = __uint_as_float(h & 0xFFFF0000u);
  lo = cvtpk(a - ra, b - rb);
  return h;
}
// v_rcp_f32: 1 ulp relative error (vs ~12-instr IEEE div) — safe for 1/x
// features since error is RELATIVE (1/(sin+eps)~1e6 -> abs err ~0.1).
__device__ __forceinline__ float frcp(float x) {
  float r;
  asm("v_rcp_f32 %0, %1" : "=v"(r) : "v"(x));
  return r;
}
// v_exp_f32: 2^x -> exp(x) via x*log2(e); rel err ~1e-7.
__device__ __forceinline__ float fexp(float x) {
  float t = x * 1.44269504088896f;
  float r;
  asm("v_exp_f32 %0, %1" : "=v"(r) : "v"(t));
  return r;
}

// ---------------------------------------------------------------------------
// Weight prep: 128 blocks x 64 lanes, one 16x16x32 fragment-pair per thread.
// Interleaved layout: frag base = ((MT*KS + ks)*64 + l)*16 ; [0..7]=hi [8..15]=lo
// value = W[m = MT*16 + (l&15)][k = ks*32 + (l>>4)*8 + j]
// W1F: MT 0..15, ks 0..3 (k>=114 zero-pad)   W2F: MT 0..7, ks 0..7
// ---------------------------------------------------------------------------
__global__ __launch_bounds__(64)
void w_prep_kernel(const float* __restrict__ W1,
                   const float* __restrict__ W2,
                   short* __restrict__ W1F,
                   short* __restrict__ W2F) {
  const int g = blockIdx.x;
  const int l = threadIdx.x;
  float v[8];
  if (g < 64) {
    int mt = g >> 2, ks = g & 3;
    int m = mt * 16 + (l & 15), k0 = ks * 32 + (l >> 4) * 8;
#pragma unroll
    for (int j = 0; j < 8; j++)
      v[j] = (k0 + j < 114) ? W1[m * 114 + k0 + j] : 0.0f;
    u32x4 hi, lo;
#pragma unroll
    for (int i = 0; i < 4; i++) {
      unsigned lt;
      hi[i] = split2(v[2 * i], v[2 * i + 1], lt);
      lo[i] = lt;
    }
    int base = ((mt * 4 + ks) * 64 + l) * 16;
    *(u32x4*)&W1F[base] = hi;
    *(u32x4*)&W1F[base + 8] = lo;
  } else {
    int t = g - 64;
    int mt = t >> 3, ks = t & 7;
    int m = mt * 16 + (l & 15), k0 = ks * 32 + (l >> 4) * 8;
#pragma unroll
    for (int j = 0; j < 8; j++) v[j] = W2[m * 256 + k0 + j];
    u32x4 hi, lo;
#pragma unroll
    for (int i = 0; i < 4; i++) {
      unsigned lt;
      hi[i] = split2(v[2 * i], v[2 * i + 1], lt);
      lo[i] = lt;
    }
    int base = ((mt * 8 + ks) * 64 + l) * 16;
    *(u32x4*)&W2F[base] = hi;
    *(u32x4*)&W2F[base + 8] = lo;
  }
}

// ---------------------------------------------------------------------------
// En + Er fused: one block (512 thr, 8 waves) per batch. 16x16x32 bf16 MFMA,
// hi/lo 3-pass. Waves 0-5: features; wave 6: stash/Cn/pad; wave 7 lanes 0-7: Er.
// uni (64KB union, plane-interleaved):
//   fea view: row r = [128 hi][128 lo] shorts, idx = r*256 + (k^rsw), lo +128
//   h1  view: row r = [256 hi][256 lo] shorts, idx = r*512 + (o^rsw), lo +256
//   rsw = (r&7)<<3 (bank byte bits 4-6)
// Weight-fragment hi-planes double-buffered (prefetch next ks under MFMA).
// L3 folded into L2 epilogue. ~69.5KB LDS, <=128 VGPR -> 2 blocks/CU.
// ---------------------------------------------------------------------------
__global__ __launch_bounds__(512, 4)
void en_kernel(const float* __restrict__ Pn, const float* __restrict__ Pego,
               const float* __restrict__ Vn, const float* __restrict__ Vego,
               const float* __restrict__ Cn,
               const float* __restrict__ W_s1, const float* __restrict__ b_s1,
               const float* __restrict__ b1, const float* __restrict__ b2,
               const float* __restrict__ W3, const float* __restrict__ b3,
               const float* __restrict__ Ww, const float* __restrict__ bw,
               const float* __restrict__ ego_y,
               const float* __restrict__ W_sel, const float* __restrict__ b_sel,
               const float* __restrict__ W_s0, const float* __restrict__ b_s0,
               const float* __restrict__ W_map, const float* __restrict__ b_map,
               const float* __restrict__ W_efc, const float* __restrict__ b_efc,
               const short* __restrict__ W1F, const short* __restrict__ W2F,
               float* __restrict__ out) {
  __shared__ __align__(16) short uni[64 * 512];
  __shared__ float stash[4 * 64];
  __shared__ float w3s[256];
  __shared__ float b1s[256];
  __shared__ float b2s[128];
  __shared__ float en_part[4][64][2];

  const int b = blockIdx.x;
  const int tid = threadIdx.x;
  const int w = tid >> 6;   // wave 0..7
  const int l = tid & 63;
  const int lr = l & 15;    // fragment row/col index
  const int lq = l >> 4;    // k-quad
  const int ntb = (w >> 2) * 2;  // this wave's row-tile base (2 tiles)

  if (tid < 256) { w3s[tid] = W3[tid]; b1s[tid] = b1[tid]; }
  else if (tid < 384) b2s[tid - 256] = b2[tid - 256];

  // ---------------- phase 0: features / stash / Er, wave-specialized --------
  {
    const int r = l;
    const int rsw = (r & 7) << 3;
    auto putg = [&](int g, const float* v) {
      u32x4 hi, lo;
#pragma unroll
      for (int i = 0; i < 4; i++) {
        unsigned lt;
        hi[i] = split2(v[2 * i], v[2 * i + 1], lt);
        lo[i] = lt;
      }
      int idx = r * 256 + ((g * 8) ^ rsw);
      *(u32x4*)&uni[idx] = hi;
      *(u32x4*)&uni[idx + 128] = lo;
    };
    if (w == 6) {
      const float2 p2 = ((const float2*)Pn)[b * NN + r];
      float e0 = Pego[b * 2 + 0], e1 = Pego[b * 2 + 1];
      stash[0 * 64 + r] = p2.x; stash[1 * 64 + r] = p2.y;
      stash[2 * 64 + r] = p2.x - e0; stash[3 * 64 + r] = p2.y - e1;
      const float2 cn = ((const float2*)Cn)[b * NN + r];
      float g14[8] = {cn.x, cn.y, 0.f, 0.f, 0.f, 0.f, 0.f, 0.f};
      float g15[8] = {0.f, 0.f, 0.f, 0.f, 0.f, 0.f, 0.f, 0.f};
      putg(14, g14);
      putg(15, g15);
    } else if (w < 6) {
      const bool isV = (w >= 3);
      const int role = isV ? (w - 3) : w;
      const int gb = isV ? 7 : 0;
      const float2 p2 = ((const float2*)(isV ? Vn : Pn))[b * NN + r];
      const float* Eb = isV ? Vego : Pego;
      float e0 = Eb[b * 2 + 0], e1 = Eb[b * 2 + 1];
      float d0 = p2.x - e0, d1 = p2.y - e1;
      if (role == 0) {
        float a15 = fmaf(W_s1[30], d0, fmaf(W_s1[31], d1, b_s1[15]));
        float a16 = fmaf(W_s1[32], d0, fmaf(W_s1[33], d1, b_s1[16]));
        float s15 = sinf(a15) + EPS, s16 = sinf(a16) + EPS;
        float q0 = d0 * d0 + EPS, q1 = d1 * d1 + EPS;
        float c30 = (d0 * d0) * d0 + EPS, c31 = (d1 * d1) * d1 + EPS;
        float ex0 = fexp(d0) + EPS, ex1 = fexp(d1) + EPS;
        float g0[8] = {e0, e1, p2.x, p2.y, d0, d1, d0, d1};
        float g3[8] = {s16, q0, q1, c30, c31, ex0, ex1, frcp(d0 + EPS)};
        float g6[8] = {frcp(s15), frcp(s16), frcp(q0), frcp(q1),
                       frcp(c30), frcp(c31), frcp(ex0), frcp(ex1)};
        putg(gb + 0, g0);
        putg(gb + 3, g3);
        putg(gb + 6, g6);
      } else if (role == 1) {
        float s[8];
#pragma unroll
        for (int i = 0; i < 8; i++) {
          float a = fmaf(W_s1[2 * i], d0, fmaf(W_s1[2 * i + 1], d1, b_s1[i]));
          s[i] = sinf(a) + EPS;
        }
        float g1[8] = {s[0], s[1], s[2], s[3], s[4], s[5], s[6], s[7]};
        float g4[8] = {frcp(d1 + EPS), frcp(s[0]), frcp(s[1]), frcp(s[2]),
                       frcp(s[3]), frcp(s[4]), frcp(s[5]), frcp(s[6])};
        putg(gb + 1, g1);
        putg(gb + 4, g4);
      } else {
        float s[9];  // sins 7..15
#pragma unroll
        for (int i = 0; i < 9; i++) {
          float a = fmaf(W_s1[2 * (7 + i)], d0,
                         fmaf(W_s1[2 * (7 + i) + 1], d1, b_s1[7 + i]));
          s[i] = sinf(a) + EPS;
        }
        float g2[8] = {s[1], s[2], s[3], s[4], s[5], s[6], s[7], s[8]};
        float g5[8] = {frcp(s[0]), frcp(s[1]), frcp(s[2]), frcp(s[3]),
                       frcp(s[4]), frcp(s[5]), frcp(s[6]), frcp(s[7])};
        putg(gb + 2, g2);
        putg(gb + 5, g5);
      }
    } else if (l < 8) {
      // ---- Er net, 8 lanes of wave 7 ----
      const int sub = l;
      const float lane4[4] = {13.55f, 17.45f, 21.12f, 24.91f};
      float ego = ego_y[b];
      float dy[4];
#pragma unroll
      for (int j = 0; j < 4; j++) dy[j] = lane4[j] - ego;
      float t[4];
#pragma unroll
      for (int i = 0; i < 4; i++) {
        float a = b_sel[i];
#pragma unroll
        for (int j = 0; j < 4; j++) a = fmaf(W_sel[i * 4 + j], dy[j], a);
        t[i] = a;
      }
      float m = fmaxf(fmaxf(t[0], t[1]), fmaxf(t[2], t[3]));
      float e[4], s = 0.f;
#pragma unroll
      for (int i = 0; i < 4; i++) { e[i] = fexp(t[i] - m); s += e[i]; }
      float rs = frcp(s);
      float x[4];
#pragma unroll
      for (int i = 0; i < 4; i++) x[i] = (e[i] * rs) * dy[i];
      float f[48];
      float sn[8];
#pragma unroll
      for (int k = 0; k < 8; k++) {
        float a = b_s0[k];
#pragma unroll
        for (int j = 0; j < 4; j++) a = fmaf(W_s0[k * 4 + j], x[j], a);
        sn[k] = sinf(a) + EPS;
      }
#pragma unroll
      for (int i = 0; i < 4; i++) f[i] = x[i];
#pragma unroll
      for (int k = 0; k < 8; k++) f[4 + k] = sn[k];
#pragma unroll
      for (int i = 0; i < 4; i++) {
        float q = x[i] * x[i] + EPS;
        f[12 + i] = q; f[36 + i] = frcp(q);
      }
#pragma unroll
      for (int i = 0; i < 4; i++) {
        float c3 = (x[i] * x[i]) * x[i] + EPS;
        f[16 + i] = c3; f[40 + i] = frcp(c3);
      }
#pragma unroll
      for (int i = 0; i < 4; i++) {
        float ex = fexp(x[i]) + EPS;
        f[20 + i] = ex; f[44 + i] = frcp(ex);
      }
#pragma unroll
      for (int i = 0; i < 4; i++) f[24 + i] = frcp(x[i] + EPS);
#pragma unroll
      for (int k = 0; k < 8; k++) f[28 + k] = frcp(sn[k]);
      float a = b_map[sub];
#pragma unroll
      for (int k = 0; k < 48; k++) a = fmaf(W_map[sub * 48 + k], f[k], a);
      float y = fmaxf(a, 0.1f * a);
      float t0 = W_efc[sub] * y;
      float t1 = W_efc[8 + sub] * y;
#pragma unroll
      for (int off = 4; off > 0; off >>= 1) {
        t0 += __shfl_xor(t0, off);
        t1 += __shfl_xor(t1, off);
      }
      if (sub == 0) {
        out[b * 4 + 0] = t0 + b_efc[0];
        out[b * 4 + 1] = t1 + b_efc[1];
      }
    }
  }
  __syncthreads();

  // ---------------- layer 1: [256 o] x [64 r], K=128 (4m x 2n) ----------------
  // hi-plane weight frags double-buffered: prefetch ks+1 while MFMA on ks.
  const short* w1b = W1F + l * 16;   // + (MT*4 + ks)*1024, MT = (w&3)*4 + m
  f32x4 acc1[4][2];
#pragma unroll
  for (int m = 0; m < 4; m++)
#pragma unroll
    for (int n = 0; n < 2; n++) acc1[m][n] = (f32x4)0.0f;

  short8_t ch[4];
#pragma unroll
  for (int m = 0; m < 4; m++)
    ch[m] = *(const short8_t*)&w1b[(((w & 3) * 4 + m) * 4 + 0) * 1024];

#pragma unroll
  for (int ks = 0; ks < 4; ks++) {
    short8_t nh[4];
    if (ks < 3) {
#pragma unroll
      for (int m = 0; m < 4; m++)
        nh[m] = *(const short8_t*)&w1b[(((w & 3) * 4 + m) * 4 + ks + 1) * 1024];
    }
    short8_t cl[4];
#pragma unroll
    for (int m = 0; m < 4; m++)
      cl[m] = *(const short8_t*)&w1b[(((w & 3) * 4 + m) * 4 + ks) * 1024 + 8];
    short8_t bh[2], bl[2];
#pragma unroll
    for (int n = 0; n < 2; n++) {
      int rr = (ntb + n) * 16 + lr;
      int idx = rr * 256 + ((ks * 32 + lq * 8) ^ ((rr & 7) << 3));
      bh[n] = *(const short8_t*)&uni[idx];
      bl[n] = *(const short8_t*)&uni[idx + 128];
    }
    __builtin_amdgcn_s_setprio(1);
#pragma unroll
    for (int m = 0; m < 4; m++)
#pragma unroll
      for (int n = 0; n < 2; n++)
        acc1[m][n] = __builtin_amdgcn_mfma_f32_16x16x32_bf16(
            ch[m], bh[n], acc1[m][n], 0, 0, 0);
#pragma unroll
    for (int m = 0; m < 4; m++)
#pragma unroll
      for (int n = 0; n < 2; n++)
        acc1[m][n] = __builtin_amdgcn_mfma_f32_16x16x32_bf16(
            ch[m], bl[n], acc1[m][n], 0, 0, 0);
#pragma unroll
    for (int m = 0; m < 4; m++)
#pragma unroll
      for (int n = 0; n < 2; n++)
        acc1[m][n] = __builtin_amdgcn_mfma_f32_16x16x32_bf16(
            cl[m], bh[n], acc1[m][n], 0, 0, 0);
    __builtin_amdgcn_s_setprio(0);
    if (ks < 3) {
#pragma unroll
      for (int m = 0; m < 4; m++) ch[m] = nh[m];
    }
  }

  // all fea reads done before h1 overwrites the union buffer
  __syncthreads();

  // ---- L1 epilogue: bias + leaky + cvt_pk hi/lo split -> h1 view ----
#pragma unroll
  for (int m = 0; m < 4; m++) {
    int o0 = ((w & 3) * 4 + m) * 16 + lq * 4;
    f32x4 bb = *(const f32x4*)&b1s[o0];
#pragma unroll
    for (int n = 0; n < 2; n++) {
      int rr = (ntb + n) * 16 + lr;
      float v0 = fmaxf(acc1[m][n][0] + bb[0], 0.1f * (acc1[m][n][0] + bb[0]));
      float v1 = fmaxf(acc1[m][n][1] + bb[1], 0.1f * (acc1[m][n][1] + bb[1]));
      float v2 = fmaxf(acc1[m][n][2] + bb[2], 0.1f * (acc1[m][n][2] + bb[2]));
      float v3 = fmaxf(acc1[m][n][3] + bb[3], 0.1f * (acc1[m][n][3] + bb[3]));
      u32x2 hi, lo;
      unsigned l0, l1;
      hi[0] = split2(v0, v1, l0);
      hi[1] = split2(v2, v3, l1);
      lo[0] = l0;
      lo[1] = l1;
      int idx = rr * 512 + (o0 ^ ((rr & 7) << 3));
      *(u32x2*)&uni[idx] = hi;
      *(u32x2*)&uni[idx + 256] = lo;
    }
  }
  __syncthreads();

  // ---------------- layer 2: [128 o] x [64 r], K=256 (2m x 2n) ----------------
  const short* w2b = W2F + l * 16;   // + (MT*8 + ks)*1024, MT = (w&3)*2 + m
  f32x4 acc2[2][2];
#pragma unroll
  for (int m = 0; m < 2; m++)
#pragma unroll
    for (int n = 0; n < 2; n++) acc2[m][n] = (f32x4)0.0f;

  short8_t ch2[2];
#pragma unroll
  for (int m = 0; m < 2; m++)
    ch2[m] = *(const short8_t*)&w2b[(((w & 3) * 2 + m) * 8 + 0) * 1024];

#pragma unroll
  for (int ks = 0; ks < 8; ks++) {
    short8_t nh[2];
    if (ks < 7) {
#pragma unroll
      for (int m = 0; m < 2; m++)
        nh[m] = *(const short8_t*)&w2b[(((w & 3) * 2 + m) * 8 + ks + 1) * 1024];
    }
    short8_t cl[2];
#pragma unroll
    for (int m = 0; m < 2; m++)
      cl[m] = *(const short8_t*)&w2b[(((w & 3) * 2 + m) * 8 + ks) * 1024 + 8];
    short8_t bh[2], bl[2];
#pragma unroll
    for (int n = 0; n < 2; n++) {
      int rr = (ntb + n) * 16 + lr;
      int idx = rr * 512 + ((ks * 32 + lq * 8) ^ ((rr & 7) << 3));
      bh[n] = *(const short8_t*)&uni[idx];
      bl[n] = *(const short8_t*)&uni[idx + 256];
    }
    __builtin_amdgcn_s_setprio(1);
#pragma unroll
    for (int m = 0; m < 2; m++)
#pragma unroll
      for (int n = 0; n < 2; n++)
        acc2[m][n] = __builtin_amdgcn_mfma_f32_16x16x32_bf16(
            ch2[m], bh[n], acc2[m][n], 0, 0, 0);
#pragma unroll
    for (int m = 0; m < 2; m++)
#pragma unroll
      for (int n = 0; n < 2; n++)
        acc2[m][n] = __builtin_amdgcn_mfma_f32_16x16x32_bf16(
            ch2[m], bl[n], acc2[m][n], 0, 0, 0);
#pragma unroll
    for (int m = 0; m < 2; m++)
#pragma unroll
      for (int n = 0; n < 2; n++)
        acc2[m][n] = __builtin_amdgcn_mfma_f32_16x16x32_bf16(
            cl[m], bh[n], acc2[m][n], 0, 0, 0);
    __builtin_amdgcn_s_setprio(0);
    if (ks < 7) {
#pragma unroll
      for (int m = 0; m < 2; m++) ch2[m] = nh[m];
    }
  }

  // ---- L2 epilogue fused with layer 3 (in-register W3 dot) ----
  {
    f32x4 w3v[2][2];  // [c][m]
#pragma unroll
    for (int c = 0; c < 2; c++)
#pragma unroll
      for (int m = 0; m < 2; m++)
        w3v[c][m] = *(const f32x4*)
            &w3s[c * 128 + ((w & 3) * 2 + m) * 16 + lq * 4];

    float p00 = 0.f, p01 = 0.f, p10 = 0.f, p11 = 0.f;  // p[c][n]
#pragma unroll
    for (int m = 0; m < 2; m++) {
      int o0 = ((w & 3) * 2 + m) * 16 + lq * 4;
      f32x4 bb = *(const f32x4*)&b2s[o0];
#pragma unroll
      for (int i = 0; i < 4; i++) {
        float u0 = acc2[m][0][i] + bb[i];
        u0 = fmaxf(u0, 0.1f * u0);
        float u1 = acc2[m][1][i] + bb[i];
        u1 = fmaxf(u1, 0.1f * u1);
        p00 = fmaf(u0, w3v[0][m][i], p00);
        p10 = fmaf(u0, w3v[1][m][i], p10);
        p01 = fmaf(u1, w3v[0][m][i], p01);
        p11 = fmaf(u1, w3v[1][m][i], p11);
      }
    }
    // sum the 4 lq-groups: lanes l, l^16, l^32, l^48 share lr (same row)
#pragma unroll
    for (int off = 16; off < 64; off <<= 1) {
      p00 += __shfl_xor(p00, off);
      p01 += __shfl_xor(p01, off);
      p10 += __shfl_xor(p10, off);
      p11 += __shfl_xor(p11, off);
    }
    if (l < 16) {
      en_part[w & 3][ntb * 16 + l][0] = p00;
      en_part[w & 3][ntb * 16 + l][1] = p10;
      en_part[w & 3][(ntb + 1) * 16 + l][0] = p01;
      en_part[w & 3][(ntb + 1) * 16 + l][1] = p11;
    }
  }
  __syncthreads();

  // ---------------- logits + softmax over neighbors + reduce ----------------
  if (tid < 64) {
    const int r = tid;
    float E0 = b3[0] + en_part[0][r][0] + en_part[1][r][0] +
               en_part[2][r][0] + en_part[3][r][0];
    float E1 = b3[1] + en_part[0][r][1] + en_part[1][r][1] +
               en_part[2][r][1] + en_part[3][r][1];
    float pn0 = stash[0 * 64 + r], pn1 = stash[1 * 64 + r];
    float dp0 = stash[2 * 64 + r], dp1 = stash[3 * 64 + r];
    float logit = bw[0];
    logit = fmaf(E0, Ww[0], logit);
    logit = fmaf(E1, Ww[1], logit);
    logit = fmaf(pn0, Ww[2], logit);
    logit = fmaf(pn1, Ww[3], logit);
    logit = fmaf(dp0, Ww[4], logit);
    logit = fmaf(dp1, Ww[5], logit);
    float m = logit;
#pragma unroll
    for (int off = 32; off > 0; off >>= 1) m = fmaxf(m, __shfl_xor(m, off));
    float e = fexp(logit - m);
    float ssum = e;
#pragma unroll
    for (int off = 32; off > 0; off >>= 1) ssum += __shfl_xor(ssum, off);
    float wgt = e * frcp(ssum);
    float o0 = wgt * E0, o1 = wgt * E1;
#pragma unroll
    for (int off = 32; off > 0; off >>= 1) {
      o0 += __shfl_xor(o0, off);
      o1 += __shfl_xor(o1, off);
    }
    if (r == 0) {
      out[b * 4 + 2] = o0;
      out[b * 4 + 3] = o1;
    }
  }
}

// ---------------------------------------------------------------------------
extern "C" void kernel_launch(void* const* d_in, const int* in_sizes, int n_in,
                              void* d_out, int out_size, void* d_ws, size_t ws_size,
                              hipStream_t stream) {
  const float* ego_y = (const float*)d_in[0];
  const float* Pn    = (const float*)d_in[1];
  const float* Pego  = (const float*)d_in[2];
  const float* Vn    = (const float*)d_in[3];
  const float* Vego  = (const float*)d_in[4];
  const float* Cn    = (const float*)d_in[5];
  const float* W_sel = (const float*)d_in[6];
  const float* b_sel = (const float*)d_in[7];
  const float* W_s0  = (const float*)d_in[8];
  const float* b_s0  = (const float*)d_in[9];
  const float* W_map = (const float*)d_in[10];
  const float* b_map = (const float*)d_in[11];
  const float* W_efc = (const float*)d_in[12];
  const float* b_efc = (const float*)d_in[13];
  const float* W_s1  = (const float*)d_in[14];
  const float* b_s1  = (const float*)d_in[15];
  const float* W1    = (const float*)d_in[16];
  const float* b1    = (const float*)d_in[17];
  const float* W2    = (const float*)d_in[18];
  const float* b2    = (const float*)d_in[19];
  const float* W3    = (const float*)d_in[20];
  const float* b3    = (const float*)d_in[21];
  const float* Ww    = (const float*)d_in[22];
  const float* bw    = (const float*)d_in[23];
  float* out = (float*)d_out;

  short* W1F = (short*)d_ws;          // 65536 shorts (interleaved hi/lo) 128 KB
  short* W2F = W1F + 65536;           // 65536 shorts                    128 KB

  w_prep_kernel<<<128, 64, 0, stream>>>(W1, W2, W1F, W2F);
  en_kernel<<<NB, 512, 0, stream>>>(Pn, Pego, Vn, Vego, Cn, W_s1, b_s1,
                                    b1, b2, W3, b3, Ww, bw,
                                    ego_y, W_sel, b_sel, W_s0, b_s0,
                                    W_map, b_map, W_efc, b_efc,
                                    W1F, W2F, out);
}

// Round 11
// 207.792 us; speedup vs baseline: 1.1735x; 1.1735x over previous
//
#include <hip/hip_runtime.h>
#include <math.h>

#define EPS 1e-6f
#define NB 4096
#define NN 64

typedef __attribute__((ext_vector_type(8))) short short8_t;
typedef __attribute__((ext_vector_type(4))) float f32x4;
typedef __attribute__((ext_vector_type(4))) unsigned u32x4;
typedef __attribute__((ext_vector_type(2))) unsigned u32x2;

// one instruction: packs {bf16(a), bf16(b)} (RNE) into 32 bits
__device__ __forceinline__ unsigned cvtpk(float a, float b) {
  unsigned r;
  asm("v_cvt_pk_bf16_f32 %0, %1, %2" : "=v"(r) : "v"(a), "v"(b));
  return r;
}
// split two f32 into packed bf16 hi + packed bf16 lo (2-term split)
__device__ __forceinline__ unsigned split2(float a, float b, unsigned& lo) {
  unsigned h = cvtpk(a, b);
  float ra = __uint_as_float(h << 16);
  float rb = __uint_as_float(h & 0xFFFF0000u);
  lo = cvtpk(a - ra, b - rb);
  return h;
}
// v_rcp_f32: ~1 ulp RELATIVE error (vs ~12-instr IEEE div) — verified r10,
// absmax unchanged at 1536.
__device__ __forceinline__ float frcp(float x) {
  float r;
  asm("v_rcp_f32 %0, %1" : "=v"(r) : "v"(x));
  return r;
}
// v_exp_f32: 2^x -> exp(x) via x*log2(e); rel err ~1e-7 (verified r10).
__device__ __forceinline__ float fexp(float x) {
  float t = x * 1.44269504088896f;
  float r;
  asm("v_exp_f32 %0, %1" : "=v"(r) : "v"(t));
  return r;
}

// ---------------------------------------------------------------------------
// Weight prep: 128 blocks x 64 lanes, one 16x16x32 fragment-pair per thread.
// Interleaved layout: frag base = ((MT*KS + ks)*64 + l)*16 ; [0..7]=hi [8..15]=lo
// value = W[m = MT*16 + (l&15)][k = ks*32 + (l>>4)*8 + j]
// W1F: MT 0..15, ks 0..3 (k>=114 zero-pad)   W2F: MT 0..7, ks 0..7
// ---------------------------------------------------------------------------
__global__ __launch_bounds__(64)
void w_prep_kernel(const float* __restrict__ W1,
                   const float* __restrict__ W2,
                   short* __restrict__ W1F,
                   short* __restrict__ W2F) {
  const int g = blockIdx.x;
  const int l = threadIdx.x;
  float v[8];
  if (g < 64) {
    int mt = g >> 2, ks = g & 3;
    int m = mt * 16 + (l & 15), k0 = ks * 32 + (l >> 4) * 8;
#pragma unroll
    for (int j = 0; j < 8; j++)
      v[j] = (k0 + j < 114) ? W1[m * 114 + k0 + j] : 0.0f;
    u32x4 hi, lo;
#pragma unroll
    for (int i = 0; i < 4; i++) {
      unsigned lt;
      hi[i] = split2(v[2 * i], v[2 * i + 1], lt);
      lo[i] = lt;
    }
    int base = ((mt * 4 + ks) * 64 + l) * 16;
    *(u32x4*)&W1F[base] = hi;
    *(u32x4*)&W1F[base + 8] = lo;
  } else {
    int t = g - 64;
    int mt = t >> 3, ks = t & 7;
    int m = mt * 16 + (l & 15), k0 = ks * 32 + (l >> 4) * 8;
#pragma unroll
    for (int j = 0; j < 8; j++) v[j] = W2[m * 256 + k0 + j];
    u32x4 hi, lo;
#pragma unroll
    for (int i = 0; i < 4; i++) {
      unsigned lt;
      hi[i] = split2(v[2 * i], v[2 * i + 1], lt);
      lo[i] = lt;
    }
    int base = ((mt * 8 + ks) * 64 + l) * 16;
    *(u32x4*)&W2F[base] = hi;
    *(u32x4*)&W2F[base + 8] = lo;
  }
}

// ---------------------------------------------------------------------------
// En + Er fused: one block (512 thr, 8 waves) per batch. 16x16x32 bf16 MFMA,
// hi/lo 3-pass. Waves 0-5: features; wave 6: stash/Cn/pad; wave 7 lanes 0-7: Er.
// uni (64KB union, plane-interleaved):
//   fea view: row r = [128 hi][128 lo] shorts, idx = r*256 + (k^rsw), lo +128
//   h1  view: row r = [256 hi][256 lo] shorts, idx = r*512 + (o^rsw), lo +256
//   rsw = (r&7)<<3 (bank byte bits 4-6)
// NOTE r10 lesson: NO manual weight prefetch/double-buffer — compiler+TLP
// schedules the streamed loads; manual version spilled (49MB scratch writes).
// L3 folded into L2 epilogue. ~69.5KB LDS, <=128 VGPR -> 2 blocks/CU.
// ---------------------------------------------------------------------------
__global__ __launch_bounds__(512, 4)
void en_kernel(const float* __restrict__ Pn, const float* __restrict__ Pego,
               const float* __restrict__ Vn, const float* __restrict__ Vego,
               const float* __restrict__ Cn,
               const float* __restrict__ W_s1, const float* __restrict__ b_s1,
               const float* __restrict__ b1, const float* __restrict__ b2,
               const float* __restrict__ W3, const float* __restrict__ b3,
               const float* __restrict__ Ww, const float* __restrict__ bw,
               const float* __restrict__ ego_y,
               const float* __restrict__ W_sel, const float* __restrict__ b_sel,
               const float* __restrict__ W_s0, const float* __restrict__ b_s0,
               const float* __restrict__ W_map, const float* __restrict__ b_map,
               const float* __restrict__ W_efc, const float* __restrict__ b_efc,
               const short* __restrict__ W1F, const short* __restrict__ W2F,
               float* __restrict__ out) {
  __shared__ __align__(16) short uni[64 * 512];
  __shared__ float stash[4 * 64];
  __shared__ float w3s[256];
  __shared__ float b1s[256];
  __shared__ float b2s[128];
  __shared__ float en_part[4][64][2];

  const int b = blockIdx.x;
  const int tid = threadIdx.x;
  const int w = tid >> 6;   // wave 0..7
  const int l = tid & 63;
  const int lr = l & 15;    // fragment row/col index
  const int lq = l >> 4;    // k-quad
  const int ntb = (w >> 2) * 2;  // this wave's row-tile base (2 tiles)

  if (tid < 256) { w3s[tid] = W3[tid]; b1s[tid] = b1[tid]; }
  else if (tid < 384) b2s[tid - 256] = b2[tid - 256];

  // ---------------- phase 0: features / stash / Er, wave-specialized --------
  {
    const int r = l;
    const int rsw = (r & 7) << 3;
    auto putg = [&](int g, const float* v) {
      u32x4 hi, lo;
#pragma unroll
      for (int i = 0; i < 4; i++) {
        unsigned lt;
        hi[i] = split2(v[2 * i], v[2 * i + 1], lt);
        lo[i] = lt;
      }
      int idx = r * 256 + ((g * 8) ^ rsw);
      *(u32x4*)&uni[idx] = hi;
      *(u32x4*)&uni[idx + 128] = lo;
    };
    if (w == 6) {
      const float2 p2 = ((const float2*)Pn)[b * NN + r];
      float e0 = Pego[b * 2 + 0], e1 = Pego[b * 2 + 1];
      stash[0 * 64 + r] = p2.x; stash[1 * 64 + r] = p2.y;
      stash[2 * 64 + r] = p2.x - e0; stash[3 * 64 + r] = p2.y - e1;
      const float2 cn = ((const float2*)Cn)[b * NN + r];
      float g14[8] = {cn.x, cn.y, 0.f, 0.f, 0.f, 0.f, 0.f, 0.f};
      float g15[8] = {0.f, 0.f, 0.f, 0.f, 0.f, 0.f, 0.f, 0.f};
      putg(14, g14);
      putg(15, g15);
    } else if (w < 6) {
      const bool isV = (w >= 3);
      const int role = isV ? (w - 3) : w;
      const int gb = isV ? 7 : 0;
      const float2 p2 = ((const float2*)(isV ? Vn : Pn))[b * NN + r];
      const float* Eb = isV ? Vego : Pego;
      float e0 = Eb[b * 2 + 0], e1 = Eb[b * 2 + 1];
      float d0 = p2.x - e0, d1 = p2.y - e1;
      if (role == 0) {
        float a15 = fmaf(W_s1[30], d0, fmaf(W_s1[31], d1, b_s1[15]));
        float a16 = fmaf(W_s1[32], d0, fmaf(W_s1[33], d1, b_s1[16]));
        float s15 = sinf(a15) + EPS, s16 = sinf(a16) + EPS;
        float q0 = d0 * d0 + EPS, q1 = d1 * d1 + EPS;
        float c30 = (d0 * d0) * d0 + EPS, c31 = (d1 * d1) * d1 + EPS;
        float ex0 = fexp(d0) + EPS, ex1 = fexp(d1) + EPS;
        float g0[8] = {e0, e1, p2.x, p2.y, d0, d1, d0, d1};
        float g3[8] = {s16, q0, q1, c30, c31, ex0, ex1, frcp(d0 + EPS)};
        float g6[8] = {frcp(s15), frcp(s16), frcp(q0), frcp(q1),
                       frcp(c30), frcp(c31), frcp(ex0), frcp(ex1)};
        putg(gb + 0, g0);
        putg(gb + 3, g3);
        putg(gb + 6, g6);
      } else if (role == 1) {
        float s[8];
#pragma unroll
        for (int i = 0; i < 8; i++) {
          float a = fmaf(W_s1[2 * i], d0, fmaf(W_s1[2 * i + 1], d1, b_s1[i]));
          s[i] = sinf(a) + EPS;
        }
        float g1[8] = {s[0], s[1], s[2], s[3], s[4], s[5], s[6], s[7]};
        float g4[8] = {frcp(d1 + EPS), frcp(s[0]), frcp(s[1]), frcp(s[2]),
                       frcp(s[3]), frcp(s[4]), frcp(s[5]), frcp(s[6])};
        putg(gb + 1, g1);
        putg(gb + 4, g4);
      } else {
        float s[9];  // sins 7..15
#pragma unroll
        for (int i = 0; i < 9; i++) {
          float a = fmaf(W_s1[2 * (7 + i)], d0,
                         fmaf(W_s1[2 * (7 + i) + 1], d1, b_s1[7 + i]));
          s[i] = sinf(a) + EPS;
        }
        float g2[8] = {s[1], s[2], s[3], s[4], s[5], s[6], s[7], s[8]};
        float g5[8] = {frcp(s[0]), frcp(s[1]), frcp(s[2]), frcp(s[3]),
                       frcp(s[4]), frcp(s[5]), frcp(s[6]), frcp(s[7])};
        putg(gb + 2, g2);
        putg(gb + 5, g5);
      }
    } else if (l < 8) {
      // ---- Er net, 8 lanes of wave 7 ----
      const int sub = l;
      const float lane4[4] = {13.55f, 17.45f, 21.12f, 24.91f};
      float ego = ego_y[b];
      float dy[4];
#pragma unroll
      for (int j = 0; j < 4; j++) dy[j] = lane4[j] - ego;
      float t[4];
#pragma unroll
      for (int i = 0; i < 4; i++) {
        float a = b_sel[i];
#pragma unroll
        for (int j = 0; j < 4; j++) a = fmaf(W_sel[i * 4 + j], dy[j], a);
        t[i] = a;
      }
      float m = fmaxf(fmaxf(t[0], t[1]), fmaxf(t[2], t[3]));
      float e[4], s = 0.f;
#pragma unroll
      for (int i = 0; i < 4; i++) { e[i] = fexp(t[i] - m); s += e[i]; }
      float rs = frcp(s);
      float x[4];
#pragma unroll
      for (int i = 0; i < 4; i++) x[i] = (e[i] * rs) * dy[i];
      float f[48];
      float sn[8];
#pragma unroll
      for (int k = 0; k < 8; k++) {
        float a = b_s0[k];
#pragma unroll
        for (int j = 0; j < 4; j++) a = fmaf(W_s0[k * 4 + j], x[j], a);
        sn[k] = sinf(a) + EPS;
      }
#pragma unroll
      for (int i = 0; i < 4; i++) f[i] = x[i];
#pragma unroll
      for (int k = 0; k < 8; k++) f[4 + k] = sn[k];
#pragma unroll
      for (int i = 0; i < 4; i++) {
        float q = x[i] * x[i] + EPS;
        f[12 + i] = q; f[36 + i] = frcp(q);
      }
#pragma unroll
      for (int i = 0; i < 4; i++) {
        float c3 = (x[i] * x[i]) * x[i] + EPS;
        f[16 + i] = c3; f[40 + i] = frcp(c3);
      }
#pragma unroll
      for (int i = 0; i < 4; i++) {
        float ex = fexp(x[i]) + EPS;
        f[20 + i] = ex; f[44 + i] = frcp(ex);
      }
#pragma unroll
      for (int i = 0; i < 4; i++) f[24 + i] = frcp(x[i] + EPS);
#pragma unroll
      for (int k = 0; k < 8; k++) f[28 + k] = frcp(sn[k]);
      float a = b_map[sub];
#pragma unroll
      for (int k = 0; k < 48; k++) a = fmaf(W_map[sub * 48 + k], f[k], a);
      float y = fmaxf(a, 0.1f * a);
      float t0 = W_efc[sub] * y;
      float t1 = W_efc[8 + sub] * y;
#pragma unroll
      for (int off = 4; off > 0; off >>= 1) {
        t0 += __shfl_xor(t0, off);
        t1 += __shfl_xor(t1, off);
      }
      if (sub == 0) {
        out[b * 4 + 0] = t0 + b_efc[0];
        out[b * 4 + 1] = t1 + b_efc[1];
      }
    }
  }
  __syncthreads();

  // ---------------- layer 1: [256 o] x [64 r], K=128 (4m x 2n) ----------------
  const short* w1b = W1F + l * 16;   // + (MT*4 + ks)*1024, MT = (w&3)*4 + m
  f32x4 acc1[4][2];
#pragma unroll
  for (int m = 0; m < 4; m++)
#pragma unroll
    for (int n = 0; n < 2; n++) acc1[m][n] = (f32x4)0.0f;

#pragma unroll
  for (int ks = 0; ks < 4; ks++) {
    short8_t w1h[4], w1l[4];
#pragma unroll
    for (int m = 0; m < 4; m++) {
      int fo = (((w & 3) * 4 + m) * 4 + ks) * 1024;
      w1h[m] = *(const short8_t*)&w1b[fo];
      w1l[m] = *(const short8_t*)&w1b[fo + 8];
    }
    short8_t bh[2], bl[2];
#pragma unroll
    for (int n = 0; n < 2; n++) {
      int rr = (ntb + n) * 16 + lr;
      int idx = rr * 256 + ((ks * 32 + lq * 8) ^ ((rr & 7) << 3));
      bh[n] = *(const short8_t*)&uni[idx];
      bl[n] = *(const short8_t*)&uni[idx + 128];
    }
    __builtin_amdgcn_s_setprio(1);
#pragma unroll
    for (int m = 0; m < 4; m++)
#pragma unroll
      for (int n = 0; n < 2; n++)
        acc1[m][n] = __builtin_amdgcn_mfma_f32_16x16x32_bf16(
            w1h[m], bh[n], acc1[m][n], 0, 0, 0);
#pragma unroll
    for (int m = 0; m < 4; m++)
#pragma unroll
      for (int n = 0; n < 2; n++)
        acc1[m][n] = __builtin_amdgcn_mfma_f32_16x16x32_bf16(
            w1h[m], bl[n], acc1[m][n], 0, 0, 0);
#pragma unroll
    for (int m = 0; m < 4; m++)
#pragma unroll
      for (int n = 0; n < 2; n++)
        acc1[m][n] = __builtin_amdgcn_mfma_f32_16x16x32_bf16(
            w1l[m], bh[n], acc1[m][n], 0, 0, 0);
    __builtin_amdgcn_s_setprio(0);
  }

  // all fea reads done before h1 overwrites the union buffer
  __syncthreads();

  // ---- L1 epilogue: bias + leaky + cvt_pk hi/lo split -> h1 view ----
#pragma unroll
  for (int m = 0; m < 4; m++) {
    int o0 = ((w & 3) * 4 + m) * 16 + lq * 4;
    f32x4 bb = *(const f32x4*)&b1s[o0];
#pragma unroll
    for (int n = 0; n < 2; n++) {
      int rr = (ntb + n) * 16 + lr;
      float v0 = fmaxf(acc1[m][n][0] + bb[0], 0.1f * (acc1[m][n][0] + bb[0]));
      float v1 = fmaxf(acc1[m][n][1] + bb[1], 0.1f * (acc1[m][n][1] + bb[1]));
      float v2 = fmaxf(acc1[m][n][2] + bb[2], 0.1f * (acc1[m][n][2] + bb[2]));
      float v3 = fmaxf(acc1[m][n][3] + bb[3], 0.1f * (acc1[m][n][3] + bb[3]));
      u32x2 hi, lo;
      unsigned l0, l1;
      hi[0] = split2(v0, v1, l0);
      hi[1] = split2(v2, v3, l1);
      lo[0] = l0;
      lo[1] = l1;
      int idx = rr * 512 + (o0 ^ ((rr & 7) << 3));
      *(u32x2*)&uni[idx] = hi;
      *(u32x2*)&uni[idx + 256] = lo;
    }
  }
  __syncthreads();

  // ---------------- layer 2: [128 o] x [64 r], K=256 (2m x 2n) ----------------
  const short* w2b = W2F + l * 16;   // + (MT*8 + ks)*1024, MT = (w&3)*2 + m
  f32x4 acc2[2][2];
#pragma unroll
  for (int m = 0; m < 2; m++)
#pragma unroll
    for (int n = 0; n < 2; n++) acc2[m][n] = (f32x4)0.0f;

#pragma unroll
  for (int ks = 0; ks < 8; ks++) {
    short8_t w2h[2], w2l[2];
#pragma unroll
    for (int m = 0; m < 2; m++) {
      int fo = (((w & 3) * 2 + m) * 8 + ks) * 1024;
      w2h[m] = *(const short8_t*)&w2b[fo];
      w2l[m] = *(const short8_t*)&w2b[fo + 8];
    }
    short8_t bh[2], bl[2];
#pragma unroll
    for (int n = 0; n < 2; n++) {
      int rr = (ntb + n) * 16 + lr;
      int idx = rr * 512 + ((ks * 32 + lq * 8) ^ ((rr & 7) << 3));
      bh[n] = *(const short8_t*)&uni[idx];
      bl[n] = *(const short8_t*)&uni[idx + 256];
    }
    __builtin_amdgcn_s_setprio(1);
#pragma unroll
    for (int m = 0; m < 2; m++)
#pragma unroll
      for (int n = 0; n < 2; n++)
        acc2[m][n] = __builtin_amdgcn_mfma_f32_16x16x32_bf16(
            w2h[m], bh[n], acc2[m][n], 0, 0, 0);
#pragma unroll
    for (int m = 0; m < 2; m++)
#pragma unroll
      for (int n = 0; n < 2; n++)
        acc2[m][n] = __builtin_amdgcn_mfma_f32_16x16x32_bf16(
            w2h[m], bl[n], acc2[m][n], 0, 0, 0);
#pragma unroll
    for (int m = 0; m < 2; m++)
#pragma unroll
      for (int n = 0; n < 2; n++)
        acc2[m][n] = __builtin_amdgcn_mfma_f32_16x16x32_bf16(
            w2l[m], bh[n], acc2[m][n], 0, 0, 0);
    __builtin_amdgcn_s_setprio(0);
  }

  // ---- L2 epilogue fused with layer 3 (in-register W3 dot) ----
  {
    f32x4 w3v[2][2];  // [c][m]
#pragma unroll
    for (int c = 0; c < 2; c++)
#pragma unroll
      for (int m = 0; m < 2; m++)
        w3v[c][m] = *(const f32x4*)
            &w3s[c * 128 + ((w & 3) * 2 + m) * 16 + lq * 4];

    float p00 = 0.f, p01 = 0.f, p10 = 0.f, p11 = 0.f;  // p[c][n]
#pragma unroll
    for (int m = 0; m < 2; m++) {
      int o0 = ((w & 3) * 2 + m) * 16 + lq * 4;
      f32x4 bb = *(const f32x4*)&b2s[o0];
#pragma unroll
      for (int i = 0; i < 4; i++) {
        float u0 = acc2[m][0][i] + bb[i];
        u0 = fmaxf(u0, 0.1f * u0);
        float u1 = acc2[m][1][i] + bb[i];
        u1 = fmaxf(u1, 0.1f * u1);
        p00 = fmaf(u0, w3v[0][m][i], p00);
        p10 = fmaf(u0, w3v[1][m][i], p10);
        p01 = fmaf(u1, w3v[0][m][i], p01);
        p11 = fmaf(u1, w3v[1][m][i], p11);
      }
    }
    // sum the 4 lq-groups: lanes l, l^16, l^32, l^48 share lr (same row)
#pragma unroll
    for (int off = 16; off < 64; off <<= 1) {
      p00 += __shfl_xor(p00, off);
      p01 += __shfl_xor(p01, off);
      p10 += __shfl_xor(p10, off);
      p11 += __shfl_xor(p11, off);
    }
    if (l < 16) {
      en_part[w & 3][ntb * 16 + l][0] = p00;
      en_part[w & 3][ntb * 16 + l][1] = p10;
      en_part[w & 3][(ntb + 1) * 16 + l][0] = p01;
      en_part[w & 3][(ntb + 1) * 16 + l][1] = p11;
    }
  }
  __syncthreads();

  // ---------------- logits + softmax over neighbors + reduce ----------------
  if (tid < 64) {
    const int r = tid;
    float E0 = b3[0] + en_part[0][r][0] + en_part[1][r][0] +
               en_part[2][r][0] + en_part[3][r][0];
    float E1 = b3[1] + en_part[0][r][1] + en_part[1][r][1] +
               en_part[2][r][1] + en_part[3][r][1];
    float pn0 = stash[0 * 64 + r], pn1 = stash[1 * 64 + r];
    float dp0 = stash[2 * 64 + r], dp1 = stash[3 * 64 + r];
    float logit = bw[0];
    logit = fmaf(E0, Ww[0], logit);
    logit = fmaf(E1, Ww[1], logit);
    logit = fmaf(pn0, Ww[2], logit);
    logit = fmaf(pn1, Ww[3], logit);
    logit = fmaf(dp0, Ww[4], logit);
    logit = fmaf(dp1, Ww[5], logit);
    float m = logit;
#pragma unroll
    for (int off = 32; off > 0; off >>= 1) m = fmaxf(m, __shfl_xor(m, off));
    float e = fexp(logit - m);
    float ssum = e;
#pragma unroll
    for (int off = 32; off > 0; off >>= 1) ssum += __shfl_xor(ssum, off);
    float wgt = e * frcp(ssum);
    float o0 = wgt * E0, o1 = wgt * E1;
#pragma unroll
    for (int off = 32; off > 0; off >>= 1) {
      o0 += __shfl_xor(o0, off);
      o1 += __shfl_xor(o1, off);
    }
    if (r == 0) {
      out[b * 4 + 2] = o0;
      out[b * 4 + 3] = o1;
    }
  }
}

// ---------------------------------------------------------------------------
extern "C" void kernel_launch(void* const* d_in, const int* in_sizes, int n_in,
                              void* d_out, int out_size, void* d_ws, size_t ws_size,
                              hipStream_t stream) {
  const float* ego_y = (const float*)d_in[0];
  const float* Pn    = (const float*)d_in[1];
  const float* Pego  = (const float*)d_in[2];
  const float* Vn    = (const float*)d_in[3];
  const float* Vego  = (const float*)d_in[4];
  const float* Cn    = (const float*)d_in[5];
  const float* W_sel = (const float*)d_in[6];
  const float* b_sel = (const float*)d_in[7];
  const float* W_s0  = (const float*)d_in[8];
  const float* b_s0  = (const float*)d_in[9];
  const float* W_map = (const float*)d_in[10];
  const float* b_map = (const float*)d_in[11];
  const float* W_efc = (const float*)d_in[12];
  const float* b_efc = (const float*)d_in[13];
  const float* W_s1  = (const float*)d_in[14];
  const float* b_s1  = (const float*)d_in[15];
  const float* W1    = (const float*)d_in[16];
  const float* b1    = (const float*)d_in[17];
  const float* W2    = (const float*)d_in[18];
  const float* b2    = (const float*)d_in[19];
  const float* W3    = (const float*)d_in[20];
  const float* b3    = (const float*)d_in[21];
  const float* Ww    = (const float*)d_in[22];
  const float* bw    = (const float*)d_in[23];
  float* out = (float*)d_out;

  short* W1F = (short*)d_ws;          // 65536 shorts (interleaved hi/lo) 128 KB
  short* W2F = W1F + 65536;           // 65536 shorts                    128 KB

  w_prep_kernel<<<128, 64, 0, stream>>>(W1, W2, W1F, W2F);
  en_kernel<<<NB, 512, 0, stream>>>(Pn, Pego, Vn, Vego, Cn, W_s1, b_s1,
                                    b1, b2, W3, b3, Ww, bw,
                                    ego_y, W_sel, b_sel, W_s0, b_s0,
                                    W_map, b_map, W_efc, b_efc,
                                    W1F, W2F, out);
}